// Round 7
// baseline (485.663 us; speedup 1.0000x reference)
//
#include <hip/hip_runtime.h>
#include <stdint.h>

// VQVAE quantise, fp32 in/out.
// R7: amortize the per-iteration fixed latency (the R2-R6 invariant wall:
// every config landed 171-234 us with <=20% busy pipes, ~17k idle cy/iter).
// Same structure as R6 (grid 256 = squad x c, delivery-optimal, fused
// one-hot zeroing, plain __syncthreads, double-buffered LDS, prefetch-first)
// but TS 64->128: iterations 16->8, so each barrier/latency window is paid
// half as often and the NT-store drain window doubles. Wave remap to fit
// registers: 8 waves = 8 M-stripes of 32 rows (mi=2, A-frags 64 regs,
// acc 64, pf 32 -> ~220 unified regs, keeps 2 waves/SIMD).
// Per-element distance math / split8 / MFMA sequence / tie-break unchanged.

#define B_SZ 256
#define C_SZ 64
#define E_SZ 128
#define S_SZ 4096
#define CW   8192
#define TS   128    // dict rows staged per iter
#define SPB  1024   // S-range per block
#define NIT  (SPB / TS)   // 8 iterations
#define LDB  128    // LDS B-row stride in f16 (swizzled)

typedef __attribute__((ext_vector_type(4))) float    float4a;
typedef __attribute__((ext_vector_type(8))) _Float16 half8;

__device__ __forceinline__ int swz(int row, int cf16) {
    return row * LDB + (cf16 ^ ((row & 7) << 3));
}

__device__ __forceinline__ void split8(float4a f0, float4a f1, half8& hi, half8& lo) {
    #pragma unroll
    for (int j = 0; j < 4; ++j) {
        _Float16 h0 = (_Float16)f0[j];
        hi[j]     = h0;
        lo[j]     = (_Float16)(f0[j] - (float)h0);
        _Float16 h1 = (_Float16)f1[j];
        hi[4 + j] = h1;
        lo[4 + j] = (_Float16)(f1[j] - (float)h1);
    }
}

// grid 256 = (squad 0..3) x (c 0..63), block 512 = 8 waves (mq 0..7).
__global__ __launch_bounds__(512, 2) void argmin_mfma(
    const float* __restrict__ x,
    const float* __restrict__ dict,
    float* __restrict__ cw_out,
    float* __restrict__ oh)
{
    __shared__ __attribute__((aligned(16))) _Float16 bh[2][TS * LDB];  // 2x32 KB
    __shared__ __attribute__((aligned(16))) _Float16 bl[2][TS * LDB];  // 2x32 KB
    __shared__ __attribute__((aligned(16))) float dsqp[2][TS][4];      // 4 KB
    // final reduction tables aliased onto staging LDS (used after the loop)
    float* rv = reinterpret_cast<float*>(bh);   // 16 cols x 256 rows = 16 KB
    int*   ri = reinterpret_cast<int*>(bl);     // 16 KB

    const int tid   = threadIdx.x;
    const int lane  = tid & 63;
    const int quad  = lane >> 4;
    const int l15   = lane & 15;
    const int mq    = tid >> 6;          // wave id = M-stripe
    const int c     = blockIdx.x & 63;
    const int squad = blockIdx.x >> 6;
    const int sbase = squad * SPB;

    // ---- runtime layout probes: true (row, col) of each (lane, reg) ----
    int m_attr[4], n_attr[4];
    {
        half8 ones, enc;
        #pragma unroll
        for (int j = 0; j < 8; ++j) { ones[j] = (_Float16)1.0f; enc[j] = (_Float16)(float)l15; }
        float4a z = {0.f, 0.f, 0.f, 0.f};
        float4a pr = __builtin_amdgcn_mfma_f32_16x16x32_f16(enc, ones, z, 0, 0, 0);
        float4a pc = __builtin_amdgcn_mfma_f32_16x16x32_f16(ones, enc, z, 0, 0, 0);
        #pragma unroll
        for (int r = 0; r < 4; ++r) {
            m_attr[r] = (int)(pr[r] * 0.03125f + 0.5f);   // row feeding this element
            n_attr[r] = (int)(pc[r] * 0.03125f + 0.5f);   // col feeding this element
        }
    }

    // ---- A fragments (regs, whole kernel): wave mq owns rows [mq*32, mq*32+32) ----
    half8 ah[2][4], al[2][4];
    #pragma unroll
    for (int mi = 0; mi < 2; ++mi) {
        int b = mq * 32 + mi * 16 + l15;
        const float* xr = x + (size_t)b * CW + c * E_SZ;
        #pragma unroll
        for (int kk = 0; kk < 4; ++kk) {
            float4a f0 = *reinterpret_cast<const float4a*>(xr + kk * 32 + quad * 8);
            float4a f1 = *reinterpret_cast<const float4a*>(xr + kk * 32 + quad * 8 + 4);
            split8(f0, f1, ah[mi][kk], al[mi][kk]);
        }
    }

    // ---- staging coords: 128 rows x 128 f32, 32 f32/thread ----
    const int srow = tid >> 2;
    const int kq   = (tid & 3) * 32;
    const int q4   = tid & 3;
    const float* drow = dict + ((size_t)c * S_SZ + sbase + srow) * E_SZ + kq;

    // ---- prologue: load + convert tile 0 into buffer 0 ----
    float4a pf[8];
    #pragma unroll
    for (int ck = 0; ck < 8; ++ck)
        pf[ck] = *reinterpret_cast<const float4a*>(drow + ck * 4);
    {
        float dp = 0.f;
        #pragma unroll
        for (int ck = 0; ck < 4; ++ck) {
            half8 h, l;
            split8(pf[2 * ck], pf[2 * ck + 1], h, l);
            #pragma unroll
            for (int j = 0; j < 4; ++j) {
                dp = fmaf(pf[2 * ck][j], pf[2 * ck][j], dp);
                dp = fmaf(pf[2 * ck + 1][j], pf[2 * ck + 1][j], dp);
            }
            *reinterpret_cast<half8*>(&bh[0][swz(srow, kq + ck * 8)]) = h;
            *reinterpret_cast<half8*>(&bl[0][swz(srow, kq + ck * 8)]) = l;
        }
        dsqp[0][srow][q4] = dp;
    }

    float bestv[8];
    int   besti[8];
    #pragma unroll
    for (int i = 0; i < 8; ++i) { bestv[i] = 3.4e38f; besti[i] = 0; }

    __syncthreads();

    int cur = 0;
    for (int it = 0; it < NIT; ++it) {
        // ---- issue next tile's global loads FIRST (oldest in vmcnt queue) ----
        if (it + 1 < NIT) {
            const float* dr = drow + (size_t)(it + 1) * (TS * E_SZ);
            #pragma unroll
            for (int ck = 0; ck < 8; ++ck)
                pf[ck] = *reinterpret_cast<const float4a*>(dr + ck * 4);
        }

        // ---- zero 32 of the 256 one-hot row-slices (s in [sbase,sbase+1024)) ----
        {
            const int zrow = it * 32 + (tid >> 4);
            const int t4   = tid & 15;
            float* zb = oh + ((size_t)zrow * C_SZ + c) * S_SZ + sbase;
            float4a zz = {0.f, 0.f, 0.f, 0.f};
            #pragma unroll
            for (int j = 0; j < 16; ++j)
                __builtin_nontemporal_store(zz, reinterpret_cast<float4a*>(zb) + t4 + j * 16);
        }

        // ---- MFMA phase on buf[cur]: 192 MFMAs/wave ----
        const _Float16* bhc = bh[cur];
        const _Float16* blc = bl[cur];
        float4a acc[2][8];
        #pragma unroll
        for (int mi = 0; mi < 2; ++mi)
            #pragma unroll
            for (int ni = 0; ni < 8; ++ni)
                acc[mi][ni] = (float4a){0.f, 0.f, 0.f, 0.f};
        __builtin_amdgcn_s_setprio(1);
        #pragma unroll
        for (int kk = 0; kk < 4; ++kk) {
            #pragma unroll
            for (int ni = 0; ni < 8; ++ni) {
                const int sl = ni * 16 + l15;   // loader believes col = l15
                half8 bhf = *reinterpret_cast<const half8*>(bhc + swz(sl, kk * 32 + quad * 8));
                half8 blf = *reinterpret_cast<const half8*>(blc + swz(sl, kk * 32 + quad * 8));
                #pragma unroll
                for (int mi = 0; mi < 2; ++mi) {
                    acc[mi][ni] = __builtin_amdgcn_mfma_f32_16x16x32_f16(
                        ah[mi][kk], bhf, acc[mi][ni], 0, 0, 0);
                    acc[mi][ni] = __builtin_amdgcn_mfma_f32_16x16x32_f16(
                        ah[mi][kk], blf, acc[mi][ni], 0, 0, 0);
                    acc[mi][ni] = __builtin_amdgcn_mfma_f32_16x16x32_f16(
                        al[mi][kk], bhf, acc[mi][ni], 0, 0, 0);
                }
            }
        }
        __builtin_amdgcn_s_setprio(0);

        // ---- epilogue: dist = d_sq - 2*cross (x_sq const per (b,c): argmin-invariant) ----
        #pragma unroll
        for (int ni = 0; ni < 8; ++ni)
            #pragma unroll
            for (int r = 0; r < 4; ++r) {
                const int sl = ni * 16 + n_attr[r];   // true col attribution
                float4a qa = *reinterpret_cast<const float4a*>(&dsqp[cur][sl][0]);
                float dsq = (qa[0] + qa[1]) + (qa[2] + qa[3]);
                int sg = sbase + it * TS + sl;
                #pragma unroll
                for (int mi = 0; mi < 2; ++mi) {
                    float dist = dsq - 2.0f * acc[mi][ni][r];
                    int slot = mi * 4 + r;
                    if (dist < bestv[slot]) { bestv[slot] = dist; besti[slot] = sg; }
                }
            }

        // ---- convert prefetched tile into buf[cur^1] ----
        if (it + 1 < NIT) {
            const int nb = cur ^ 1;
            float dp = 0.f;
            #pragma unroll
            for (int ck = 0; ck < 4; ++ck) {
                half8 h, l;
                split8(pf[2 * ck], pf[2 * ck + 1], h, l);
                #pragma unroll
                for (int j = 0; j < 4; ++j) {
                    dp = fmaf(pf[2 * ck][j], pf[2 * ck][j], dp);
                    dp = fmaf(pf[2 * ck + 1][j], pf[2 * ck + 1][j], dp);
                }
                *reinterpret_cast<half8*>(&bh[nb][swz(srow, kq + ck * 8)]) = h;
                *reinterpret_cast<half8*>(&bl[nb][swz(srow, kq + ck * 8)]) = l;
            }
            dsqp[nb][srow][q4] = dp;
        }
        __syncthreads();
        cur ^= 1;
    }

    // loop-end barrier: all LDS reads done (alias rv/ri); this block's
    // s-quarter of all 256 one-hot rows is zeroed.

    // ---- dump: bijective (row 0..255) x (col 0..15) scatter, transposed
    //      (rv[col*256+row]) so the scan below is bank-conflict-free ----
    #pragma unroll
    for (int mi = 0; mi < 2; ++mi)
        #pragma unroll
        for (int r = 0; r < 4; ++r) {
            int row = mq * 32 + mi * 16 + m_attr[r];
            int col = n_attr[r];
            rv[col * 256 + row] = bestv[mi * 4 + r];
            ri[col * 256 + row] = besti[mi * 4 + r];
        }
    __syncthreads();

    if (tid < 256) {
        float bv = 3.4e38f; int bi = 0x7fffffff;
        #pragma unroll 4
        for (int j = 0; j < 16; ++j) {
            float v = rv[j * 256 + tid];
            int   i = ri[j * 256 + tid];
            if (v < bv || (v == bv && i < bi)) { bv = v; bi = i; }  // first-occurrence tie
        }
        // park (dist, idx) in the cw_out cell finalize reads-then-overwrites;
        // squad slots (2 floats each) are disjoint.
        float* cp = cw_out + (size_t)tid * CW + c * E_SZ + squad * 2;
        cp[0] = bv;
        cp[1] = __int_as_float(bi);
    }
    // kernel end drains all NT zero-stores before finalize runs
}

// grid 256 = (btile, c), 256 threads: combine 4 s-quarter candidates per row,
// write the one-hot 1.0, gather cw_embed (overwrites the candidate slab).
__global__ __launch_bounds__(256) void finalize(
    const float* __restrict__ dict,
    float* __restrict__ cw_out,
    float* __restrict__ oh)
{
    __shared__ int fid[64];
    const int c     = blockIdx.x & 63;
    const int btile = blockIdx.x >> 6;
    const int tid   = threadIdx.x;

    if (tid < 64) {
        const int row = btile * 64 + tid;
        const float* cp = cw_out + (size_t)row * CW + c * E_SZ;
        float bv = cp[0]; int bi = __float_as_int(cp[1]);
        #pragma unroll
        for (int k = 1; k < 4; ++k) {
            float v = cp[2 * k];
            // squads are s-ordered: strict < preserves global first-occurrence
            if (v < bv) { bv = v; bi = __float_as_int(cp[2 * k + 1]); }
        }
        fid[tid] = bi;
        oh[((size_t)row * C_SZ + c) * S_SZ + bi] = 1.0f;
    }
    __syncthreads();

    // gather: 64 rows x 32 float4, 4 threads/row x 8 float4 each
    const int row = tid >> 2, q = tid & 3;
    const int bi = fid[row];
    const float4a* src = reinterpret_cast<const float4a*>(
        dict + ((size_t)c * S_SZ + bi) * E_SZ) + q * 8;
    float4a* dst = reinterpret_cast<float4a*>(
        cw_out + (size_t)(btile * 64 + row) * CW + c * E_SZ) + q * 8;
    #pragma unroll
    for (int j = 0; j < 8; ++j) dst[j] = src[j];
}

extern "C" void kernel_launch(void* const* d_in, const int* in_sizes, int n_in,
                              void* d_out, int out_size, void* d_ws, size_t ws_size,
                              hipStream_t stream) {
    const float* x    = (const float*)d_in[0];
    const float* dict = (const float*)d_in[1];
    float* out = (float*)d_out;
    float* oh  = out + (size_t)B_SZ * CW;

    argmin_mfma<<<dim3(256), dim3(512), 0, stream>>>(x, dict, out, oh);
    finalize<<<dim3(256), dim3(256), 0, stream>>>(dict, out, oh);
}